// Round 12
// baseline (279.583 us; speedup 1.0000x reference)
//
#include <hip/hip_runtime.h>
#include <hip/hip_fp16.h>
#include <stdint.h>
#include <stddef.h>

#define N_NODES 100000
#define N_EDGES 6400000
#define HIDDEN 16
#define NBKT 782          /* ceil(100000/128) coarse buckets of 128 nodes */
#define CAP 8704          /* bucket region capacity: mean 8184 + 5.7 sigma */
#define P1_EPB 12288      /* edges per part1 block (48KB lsort, 60.3KB LDS) */

typedef _Float16 f16x8 __attribute__((ext_vector_type(8)));
typedef _Float16 f16x4 __attribute__((ext_vector_type(4)));
typedef float f32x4 __attribute__((ext_vector_type(4)));

__host__ __device__ inline uint32_t rotl32(uint32_t x, int n) {
    return (x << n) | (x >> (32 - n));
}

// Exact JAX threefry2x32 (20 rounds)
__host__ __device__ inline void threefry2x32(uint32_t k0, uint32_t k1,
                                             uint32_t x0, uint32_t x1,
                                             uint32_t& o0, uint32_t& o1) {
    uint32_t k2 = k0 ^ k1 ^ 0x1BD11BDAu;
    x0 += k0; x1 += k1;
    x0 += x1; x1 = rotl32(x1, 13); x1 ^= x0;
    x0 += x1; x1 = rotl32(x1, 15); x1 ^= x0;
    x0 += x1; x1 = rotl32(x1, 26); x1 ^= x0;
    x0 += x1; x1 = rotl32(x1,  6); x1 ^= x0;
    x0 += k1; x1 += k2 + 1u;
    x0 += x1; x1 = rotl32(x1, 17); x1 ^= x0;
    x0 += x1; x1 = rotl32(x1, 29); x1 ^= x0;
    x0 += x1; x1 = rotl32(x1, 16); x1 ^= x0;
    x0 += x1; x1 = rotl32(x1, 24); x1 ^= x0;
    x0 += k2; x1 += k0 + 2u;
    x0 += x1; x1 = rotl32(x1, 13); x1 ^= x0;
    x0 += x1; x1 = rotl32(x1, 15); x1 ^= x0;
    x0 += x1; x1 = rotl32(x1, 26); x1 ^= x0;
    x0 += x1; x1 = rotl32(x1,  6); x1 ^= x0;
    x0 += k0; x1 += k1 + 3u;
    x0 += x1; x1 = rotl32(x1, 17); x1 ^= x0;
    x0 += x1; x1 = rotl32(x1, 29); x1 ^= x0;
    x0 += x1; x1 = rotl32(x1, 16); x1 ^= x0;
    x0 += x1; x1 = rotl32(x1, 24); x1 ^= x0;
    x0 += k1; x1 += k2 + 4u;
    x0 += x1; x1 = rotl32(x1, 13); x1 ^= x0;
    x0 += x1; x1 = rotl32(x1, 15); x1 ^= x0;
    x0 += x1; x1 = rotl32(x1, 26); x1 ^= x0;
    x0 += x1; x1 = rotl32(x1,  6); x1 ^= x0;
    x0 += k2; x1 += k0 + 5u;
    o0 = x0; o1 = x1;
}

// dropout keep decision for flattened element j (bit-exact vs dropmask)
__device__ inline bool keep_bit(uint32_t k0, uint32_t k1, uint32_t j) {
    uint32_t a, b;
    threefry2x32(k0, k1, 0u, j, a, b);
    uint32_t bits = a ^ b;
    float u = __uint_as_float((bits >> 9) | 0x3F800000u) - 1.0f;
    return u >= 0.3f;
}

// ---- gcursor[b] = b*CAP (fixed-capacity bucket regions, no scan) ---------
__global__ void initcur_kernel(int* __restrict__ gcursor) {
    int b = threadIdx.x;
    if (b < NBKT) gcursor[b] = b * CAP;
}

// ---- partition pass 1: LDS counting sort, reg-cached dst, shuffle scan ---
// R9 lesson: occupancy is NOT the limiter (65% occ ran 40% SLOWER than 39%).
// R10: dst int4s cached in registers between hist and scatter passes; EPB
// 12288 cuts per-block fixed costs and lengthens write runs (52->~45us).
// lsort staging is load-bearing: 43MB writes with it vs 172MB without (R3).
__global__ __launch_bounds__(512) void part1_kernel(const int* __restrict__ src,
                                                    const int* __restrict__ dst,
                                                    int* __restrict__ gcursor,
                                                    int* __restrict__ buf) {
    __shared__ int lhist[NBKT], lbase[NBKT], lstart[NBKT], lcur[NBKT];
    __shared__ int wsum[8];
    __shared__ int lsort[P1_EPB];
    int tid = threadIdx.x;
    const int NV4 = N_EDGES >> 2;                 // 1.6M int4 groups
    int base4 = blockIdx.x * (P1_EPB >> 2);       // 3072 int4 per block
    const int4* dst4 = (const int4*)dst;
    const int4* src4 = (const int4*)src;

    for (int b = tid; b < NBKT; b += 512) lhist[b] = 0;
    __syncthreads();
    int4 dc[6];                                   // register dst cache
    #pragma unroll
    for (int i = 0; i < 6; i++) {
        int e4 = base4 + i * 512 + tid;
        if (e4 < NV4) dc[i] = dst4[e4];
    }
    #pragma unroll
    for (int i = 0; i < 6; i++) {
        int e4 = base4 + i * 512 + tid;
        if (e4 < NV4) {
            atomicAdd(&lhist[dc[i].x >> 7], 1);
            atomicAdd(&lhist[dc[i].y >> 7], 1);
            atomicAdd(&lhist[dc[i].z >> 7], 1);
            atomicAdd(&lhist[dc[i].w >> 7], 1);
        }
    }
    __syncthreads();
    // exclusive scan over 782 bucket counts: thread t owns buckets 2t,2t+1
    int i0 = tid * 2, i1 = i0 + 1;
    int c0 = (i0 < NBKT) ? lhist[i0] : 0;
    int c1 = (i1 < NBKT) ? lhist[i1] : 0;
    int v = c0 + c1;
    int lane = tid & 63, wid = tid >> 6;
    int sc = v;
    #pragma unroll
    for (int o = 1; o < 64; o <<= 1) {
        int t2 = __shfl_up(sc, o, 64);
        if (lane >= o) sc += t2;
    }
    if (lane == 63) wsum[wid] = sc;
    __syncthreads();
    int wo = 0;
    #pragma unroll
    for (int w = 0; w < 8; w++) wo += (w < wid) ? wsum[w] : 0;
    int excl = sc - v + wo;
    if (i0 < NBKT) { lstart[i0] = excl;      lcur[i0] = excl; }
    if (i1 < NBKT) { lstart[i1] = excl + c0; lcur[i1] = excl + c0; }
    for (int b = tid; b < NBKT; b += 512) {
        int c = lhist[b];
        lbase[b] = c ? atomicAdd(&gcursor[b], c) : 0;
    }
    __syncthreads();
    // scatter: atomics start immediately on cached dst; src loads overlap
    #pragma unroll
    for (int i = 0; i < 6; i++) {
        int e4 = base4 + i * 512 + tid;
        if (e4 < NV4) {
            int4 s = src4[e4];
            int4 d = dc[i];
            int p0 = atomicAdd(&lcur[d.x >> 7], 1);
            int p1 = atomicAdd(&lcur[d.y >> 7], 1);
            int p2 = atomicAdd(&lcur[d.z >> 7], 1);
            int p3 = atomicAdd(&lcur[d.w >> 7], 1);
            lsort[p0] = ((d.x & 127) << 17) | s.x;
            lsort[p1] = ((d.y & 127) << 17) | s.y;
            lsort[p2] = ((d.z & 127) << 17) | s.z;
            lsort[p3] = ((d.w & 127) << 17) | s.w;
        }
    }
    __syncthreads();
    int grp = tid >> 4, gl = tid & 15;
    for (int b = grp; b < NBKT; b += 32) {
        int st = lstart[b], c = lhist[b], gb = lbase[b];
        int lim = (b + 1) * CAP;
        for (int k = gl; k < c; k += 16) {
            int pos = gb + k;
            if (pos < lim)   // capacity guard (P ~ 5e-6 total)
                buf[pos] = lsort[st + k];
        }
    }
}

// ---- part2: per-bucket fine sort in LDS; reg-cached buf, shuffle scan ----
__global__ __launch_bounds__(512) void part2_kernel(const int* __restrict__ gcursor,
                                                    int* __restrict__ buf,
                                                    int* __restrict__ nodeinfo,
                                                    float* __restrict__ dinv) {
    __shared__ int lcnt[128], lcur[128];
    __shared__ int w0sum;
    __shared__ int lsort[CAP];
    int b = blockIdx.x, tid = threadIdx.x;
    int base = b * CAP;                 // CAP%4==0 -> 16B aligned
    int end = gcursor[b];
    int count = end - base;
    if (count > CAP) count = CAP;       // memory-safety clamp
    int cnt4 = count >> 2;              // <= 2176 -> <= 5 iters of 512
    const int4* buf4 = (const int4*)(buf + base);
    if (tid < 128) lcnt[tid] = 0;
    __syncthreads();
    int4 rc[5];                          // register cache (static idx only)
    #pragma unroll
    for (int it = 0; it < 5; it++) {
        int i = tid + it * 512;
        if (i < cnt4) rc[it] = buf4[i];
    }
    #pragma unroll
    for (int it = 0; it < 5; it++) {
        int i = tid + it * 512;
        if (i < cnt4) {
            atomicAdd(&lcnt[rc[it].x >> 17], 1);
            atomicAdd(&lcnt[rc[it].y >> 17], 1);
            atomicAdd(&lcnt[rc[it].z >> 17], 1);
            atomicAdd(&lcnt[rc[it].w >> 17], 1);
        }
    }
    for (int i = (cnt4 << 2) + tid; i < count; i += 512)
        atomicAdd(&lcnt[buf[base + i] >> 17], 1);
    __syncthreads();
    // shuffle scan over 128 counters (waves 0 and 1)
    if (tid < 128) {
        int v = lcnt[tid];
        int lane = tid & 63;
        int sc = v;
        #pragma unroll
        for (int o = 1; o < 64; o <<= 1) {
            int t2 = __shfl_up(sc, o, 64);
            if (lane >= o) sc += t2;
        }
        if (tid == 63) w0sum = sc;
        __syncthreads();
        int incl = sc + ((tid >= 64) ? w0sum : 0);
        int excl = incl - v;
        lcur[tid] = excl;
        int n = b * 128 + tid;
        if (n < N_NODES) {
            nodeinfo[n] = (v << 23) | (base + excl);
            dinv[n] = rsqrtf((float)v + 1.0f);  // +1 self-loop
        }
    } else {
        __syncthreads();
    }
    __syncthreads();
    #pragma unroll
    for (int it = 0; it < 5; it++) {
        int i = tid + it * 512;
        if (i < cnt4) {
            int4 w = rc[it];
            int p0 = atomicAdd(&lcur[w.x >> 17], 1); lsort[p0] = w.x & 0x1FFFF;
            int p1 = atomicAdd(&lcur[w.y >> 17], 1); lsort[p1] = w.y & 0x1FFFF;
            int p2 = atomicAdd(&lcur[w.z >> 17], 1); lsort[p2] = w.z & 0x1FFFF;
            int p3 = atomicAdd(&lcur[w.w >> 17], 1); lsort[p3] = w.w & 0x1FFFF;
        }
    }
    for (int i = (cnt4 << 2) + tid; i < count; i += 512) {
        int w = buf[base + i];
        int pos = atomicAdd(&lcur[w >> 17], 1);
        lsort[pos] = w & 0x1FFFF;
    }
    __syncthreads();
    int4* bufw4 = (int4*)(buf + base);
    const int4* lsort4 = (const int4*)lsort;
    for (int i = tid; i < cnt4; i += 512) bufw4[i] = lsort4[i];
    for (int i = (cnt4 << 2) + tid; i < count; i += 512) buf[base + i] = lsort[i];
}

// ---- LayerNorm + W1 via MFMA: 64 nodes per 256-thread block --------------
// Coalesced one-touch x load (slot-major): thread t slot j holds float4
// idx = j*256+t -> each load instr covers 4KB contiguous (R6 fix: the
// quarter-row mapping fetched 108MB = 2.1x input). Slot j of thread t holds
// row 8j+(t>>5), col (t&31)*4 -> LN stats = 32-lane shfl_xor butterfly.
#define XSTR 136
__global__ __launch_bounds__(256) void ln_w1_kernel(const float* __restrict__ x,
                             const float* __restrict__ gamma,
                             const float* __restrict__ beta,
                             const float* __restrict__ W1,
                             const float* __restrict__ dinv,
                             __half* __restrict__ g1) {
    __shared__ __align__(16) _Float16 xnh[64 * XSTR];   // 17408 B
    __shared__ __align__(16) _Float16 w1t[16 * XSTR];   //  4352 B
    int tid = threadIdx.x;

    // stage W1^T as f16: thread (n=tid&15, kb=tid>>4) covers 8 k's
    {
        int n = tid & 15, kb = tid >> 4;
        f16x8 wv;
        #pragma unroll
        for (int j = 0; j < 8; j++)
            wv[j] = (_Float16)W1[(kb * 8 + j) * 16 + n];
        *(f16x8*)&w1t[n * XSTR + kb * 8] = wv;
    }

    // coalesced loads: 8 x (256 lanes x 16B) = the full 32KB tile, one touch
    const float4* xt = (const float4*)x;
    size_t base4 = (size_t)blockIdx.x * 2048;
    const size_t NF4 = (size_t)N_NODES * 32;
    float4 v[8];
    #pragma unroll
    for (int j = 0; j < 8; j++) {
        size_t idx = base4 + (size_t)j * 256 + tid;
        v[j] = (idx < NF4) ? xt[idx] : make_float4(0.f, 0.f, 0.f, 0.f);
    }
    int col = tid & 31;            // float4 column within row
    int sub = tid >> 5;            // row sub-index within slot
    float4 gv = ((const float4*)gamma)[col];
    float4 bv = ((const float4*)beta)[col];
    #pragma unroll
    for (int j = 0; j < 8; j++) {
        float s1 = v[j].x + v[j].y + v[j].z + v[j].w;
        float s2 = v[j].x * v[j].x + v[j].y * v[j].y
                 + v[j].z * v[j].z + v[j].w * v[j].w;
        #pragma unroll
        for (int o = 1; o < 32; o <<= 1) {      // 32-lane row butterfly
            s1 += __shfl_xor(s1, o, 64);
            s2 += __shfl_xor(s2, o, 64);
        }
        float mu = s1 * (1.0f / 128.0f);
        float var = s2 * (1.0f / 128.0f) - mu * mu;
        float rstd = rsqrtf(var + 1e-5f);
        int row = j * 8 + sub;
        f16x4 h;
        h[0] = (_Float16)((v[j].x - mu) * rstd * gv.x + bv.x);
        h[1] = (_Float16)((v[j].y - mu) * rstd * gv.y + bv.y);
        h[2] = (_Float16)((v[j].z - mu) * rstd * gv.z + bv.z);
        h[3] = (_Float16)((v[j].w - mu) * rstd * gv.w + bv.w);
        *(f16x4*)&xnh[row * XSTR + col * 4] = h;
    }
    __syncthreads();

    // MFMA phase: wave w -> rows 16w..16w+15
    int l = tid & 63, w = tid >> 6;
    int am = l & 15, ak = l >> 4;   // A row / k-subgroup
    const _Float16* abase = &xnh[(w * 16 + am) * XSTR + ak * 8];
    const _Float16* bbase = &w1t[am * XSTR + ak * 8];
    f32x4 acc = {0.f, 0.f, 0.f, 0.f};
    #pragma unroll
    for (int kk = 0; kk < 4; kk++) {
        f16x8 av = *(const f16x8*)(abase + kk * 32);
        f16x8 bv2 = *(const f16x8*)(bbase + kk * 32);
        acc = __builtin_amdgcn_mfma_f32_16x16x32_f16(av, bv2, acc, 0, 0, 0);
    }
    _Float16* g1h = (_Float16*)g1;
    #pragma unroll
    for (int reg = 0; reg < 4; reg++) {
        int row = w * 16 + ak * 4 + reg;            // C: row=(l>>4)*4+reg
        int nn = blockIdx.x * 64 + row;
        if (nn < N_NODES)
            g1h[nn * 16 + am] = (_Float16)(acc[reg] * dinv[nn]);  // col=l&15
    }
}

// ---- pull conv1 + fused finalize1: 4 nodes/wave, 2x16B gather per row ----
// R11: nontemporal sorted_src loads (the 25.6MB edge stream was evicting
// the 3.2MB g1 table from per-XCD L2 -> 12MB of HBM table refetch @ 900cy;
// nt marks the stream evict-first) + 32-edge unroll (4 gathers in flight).
__global__ __launch_bounds__(256) void pull1_kernel(const int* __restrict__ nodeinfo,
                             const int* __restrict__ sorted_src,
                             const __half* __restrict__ g1,
                             const float* __restrict__ dinv,
                             const float* __restrict__ b1,
                             const float* __restrict__ W2,
                             uint32_t k10, uint32_t k11,
                             __half* __restrict__ g2) {
    __shared__ float sW2[HIDDEN * HIDDEN];
    sW2[threadIdx.x] = W2[threadIdx.x];     // 256 threads == 256 elems
    __syncthreads();
    int n = blockIdx.x * 16 + (threadIdx.x >> 4);  // grid*16 == N_NODES
    int l = threadIdx.x & 15;
    int c2 = l & 1, e8 = l >> 1;
    const _Float16* gt = (const _Float16*)g1;
    int info = nodeinfo[n];
    int start = info & 0x7FFFFF;
    int deg = (int)((unsigned)info >> 23);

    float acc[8] = {0.f,0.f,0.f,0.f,0.f,0.f,0.f,0.f};
    float acc2[8] = {0.f,0.f,0.f,0.f,0.f,0.f,0.f,0.f};
    if (e8 == 0) {                                  // self row, lanes 0,1
        f16x8 sv = *(const f16x8*)(gt + (uint32_t)n * 16 + c2 * 8);
        #pragma unroll
        for (int j = 0; j < 8; j++) acc[j] = (float)sv[j];
    }
    int km = (deg > 0) ? deg - 1 : 0;
    for (int kb = 0; kb < deg; kb += 32) {
        int k0 = kb + e8, k1 = kb + 8 + e8, k2 = kb + 16 + e8, k3 = kb + 24 + e8;
        int s0 = __builtin_nontemporal_load(sorted_src + start + min(k0, km));
        int s1 = __builtin_nontemporal_load(sorted_src + start + min(k1, km));
        int s2 = __builtin_nontemporal_load(sorted_src + start + min(k2, km));
        int s3 = __builtin_nontemporal_load(sorted_src + start + min(k3, km));
        if (k0 < deg) {
            f16x8 gv = *(const f16x8*)(gt + (uint32_t)s0 * 16 + c2 * 8);
            #pragma unroll
            for (int j = 0; j < 8; j++) acc[j] += (float)gv[j];
        }
        if (k1 < deg) {
            f16x8 gv = *(const f16x8*)(gt + (uint32_t)s1 * 16 + c2 * 8);
            #pragma unroll
            for (int j = 0; j < 8; j++) acc2[j] += (float)gv[j];
        }
        if (k2 < deg) {
            f16x8 gv = *(const f16x8*)(gt + (uint32_t)s2 * 16 + c2 * 8);
            #pragma unroll
            for (int j = 0; j < 8; j++) acc[j] += (float)gv[j];
        }
        if (k3 < deg) {
            f16x8 gv = *(const f16x8*)(gt + (uint32_t)s3 * 16 + c2 * 8);
            #pragma unroll
            for (int j = 0; j < 8; j++) acc2[j] += (float)gv[j];
        }
    }
    #pragma unroll
    for (int j = 0; j < 8; j++) acc[j] += acc2[j];
    // halving butterfly over e8: xor 2, 4, 8
    float h4[4];
    {
        int sel = e8 & 1;
        #pragma unroll
        for (int j = 0; j < 4; j++) {
            float mine = sel ? acc[j + 4] : acc[j];
            float give = sel ? acc[j] : acc[j + 4];
            h4[j] = mine + __shfl_xor(give, 2, 64);
        }
    }
    float h2[2];
    {
        int sel = (e8 >> 1) & 1;
        #pragma unroll
        for (int j = 0; j < 2; j++) {
            float mine = sel ? h4[j + 2] : h4[j];
            float give = sel ? h4[j] : h4[j + 2];
            h2[j] = mine + __shfl_xor(give, 4, 64);
        }
    }
    float hv;
    {
        int sel = (e8 >> 2) & 1;
        float mine = sel ? h2[1] : h2[0];
        float give = sel ? h2[0] : h2[1];
        hv = mine + __shfl_xor(give, 8, 64);
    }
    // lane l holds component cc
    int cc = c2 * 8 + (e8 & 1) * 4 + ((e8 >> 1) & 1) * 2 + ((e8 >> 2) & 1);
    float di = dinv[n];
    bool kp = keep_bit(k10, k11, (uint32_t)(n * 16 + cc));
    float hd = kp ? fmaxf(di * hv + b1[cc], 0.f) * (1.0f / 0.7f) : 0.f;
    // h @ W2: broadcast hd from bit-reversed lane per i (compile-time)
    int grpbase = threadIdx.x & 48;
    int c = l & 3;
    float4 o4 = make_float4(0.f, 0.f, 0.f, 0.f);
    #pragma unroll
    for (int i = 0; i < 16; i++) {
        int srcl = grpbase + (((i >> 3) & 1) | (((i >> 2) & 1) << 1) |
                              (((i >> 1) & 1) << 2) | ((i & 1) << 3));
        float hi = __shfl(hd, srcl, 64);
        const float4 w = *(const float4*)&sW2[i * HIDDEN + c * 4];
        o4.x += hi * w.x; o4.y += hi * w.y; o4.z += hi * w.z; o4.w += hi * w.w;
    }
    if (l < 4) {
        __half2 p0 = __floats2half2_rn(o4.x * di, o4.y * di);
        __half2 p1 = __floats2half2_rn(o4.z * di, o4.w * di);
        uint2 u;
        u.x = *(uint32_t*)&p0; u.y = *(uint32_t*)&p1;
        *(uint2*)((__half*)g2 + (uint32_t)n * 16 + c * 4) = u;
    }
}

// ---- pull conv2 + fused finalize2: same layout, fp32 output --------------
__global__ __launch_bounds__(256) void pull2_kernel(const int* __restrict__ nodeinfo,
                             const int* __restrict__ sorted_src,
                             const __half* __restrict__ g2,
                             const float* __restrict__ dinv,
                             const float* __restrict__ b2,
                             uint32_t k20, uint32_t k21,
                             float* __restrict__ out) {
    int n = blockIdx.x * 16 + (threadIdx.x >> 4);
    int l = threadIdx.x & 15;
    int c2 = l & 1, e8 = l >> 1;
    const _Float16* gt = (const _Float16*)g2;
    int info = nodeinfo[n];
    int start = info & 0x7FFFFF;
    int deg = (int)((unsigned)info >> 23);

    float acc[8] = {0.f,0.f,0.f,0.f,0.f,0.f,0.f,0.f};
    float acc2[8] = {0.f,0.f,0.f,0.f,0.f,0.f,0.f,0.f};
    if (e8 == 0) {                                  // self row
        f16x8 sv = *(const f16x8*)(gt + (uint32_t)n * 16 + c2 * 8);
        #pragma unroll
        for (int j = 0; j < 8; j++) acc[j] = (float)sv[j];
    }
    int km = (deg > 0) ? deg - 1 : 0;
    for (int kb = 0; kb < deg; kb += 32) {
        int k0 = kb + e8, k1 = kb + 8 + e8, k2 = kb + 16 + e8, k3 = kb + 24 + e8;
        int s0 = __builtin_nontemporal_load(sorted_src + start + min(k0, km));
        int s1 = __builtin_nontemporal_load(sorted_src + start + min(k1, km));
        int s2 = __builtin_nontemporal_load(sorted_src + start + min(k2, km));
        int s3 = __builtin_nontemporal_load(sorted_src + start + min(k3, km));
        if (k0 < deg) {
            f16x8 gv = *(const f16x8*)(gt + (uint32_t)s0 * 16 + c2 * 8);
            #pragma unroll
            for (int j = 0; j < 8; j++) acc[j] += (float)gv[j];
        }
        if (k1 < deg) {
            f16x8 gv = *(const f16x8*)(gt + (uint32_t)s1 * 16 + c2 * 8);
            #pragma unroll
            for (int j = 0; j < 8; j++) acc2[j] += (float)gv[j];
        }
        if (k2 < deg) {
            f16x8 gv = *(const f16x8*)(gt + (uint32_t)s2 * 16 + c2 * 8);
            #pragma unroll
            for (int j = 0; j < 8; j++) acc[j] += (float)gv[j];
        }
        if (k3 < deg) {
            f16x8 gv = *(const f16x8*)(gt + (uint32_t)s3 * 16 + c2 * 8);
            #pragma unroll
            for (int j = 0; j < 8; j++) acc2[j] += (float)gv[j];
        }
    }
    #pragma unroll
    for (int j = 0; j < 8; j++) acc[j] += acc2[j];
    float h4[4];
    {
        int sel = e8 & 1;
        #pragma unroll
        for (int j = 0; j < 4; j++) {
            float mine = sel ? acc[j + 4] : acc[j];
            float give = sel ? acc[j] : acc[j + 4];
            h4[j] = mine + __shfl_xor(give, 2, 64);
        }
    }
    float h2[2];
    {
        int sel = (e8 >> 1) & 1;
        #pragma unroll
        for (int j = 0; j < 2; j++) {
            float mine = sel ? h4[j + 2] : h4[j];
            float give = sel ? h4[j] : h4[j + 2];
            h2[j] = mine + __shfl_xor(give, 4, 64);
        }
    }
    float hv;
    {
        int sel = (e8 >> 2) & 1;
        float mine = sel ? h2[1] : h2[0];
        float give = sel ? h2[0] : h2[1];
        hv = mine + __shfl_xor(give, 8, 64);
    }
    int cc = c2 * 8 + (e8 & 1) * 4 + ((e8 >> 1) & 1) * 2 + ((e8 >> 2) & 1);
    float di = dinv[n];
    bool kp = keep_bit(k20, k21, (uint32_t)(n * 16 + cc));
    float r = kp ? fmaxf(di * hv + b2[cc], 0.f) * (1.0f / 0.7f) : 0.f;
    out[(uint32_t)n * 16 + cc] = r;   // 16 lanes cover one 64B line
}

extern "C" void kernel_launch(void* const* d_in, const int* in_sizes, int n_in,
                              void* d_out, int out_size, void* d_ws, size_t ws_size,
                              hipStream_t stream) {
    const float* x     = (const float*)d_in[0];
    const int*   ei    = (const int*)d_in[1];
    const float* gamma = (const float*)d_in[2];
    const float* beta  = (const float*)d_in[3];
    const float* W1    = (const float*)d_in[4];
    const float* b1    = (const float*)d_in[5];
    const float* W2    = (const float*)d_in[6];
    const float* b2    = (const float*)d_in[7];
    float* out = (float*)d_out;
    const int* src = ei;
    const int* dst = ei + N_EDGES;

    uint32_t dk1_0, dk1_1, dk2_0, dk2_1;
    threefry2x32(0u, 42u, 0u, 0u, dk1_0, dk1_1);
    threefry2x32(0u, 42u, 0u, 1u, dk2_0, dk2_1);

    // ws layout (4B elems): gcursor[1024] | nodeinfo[100k] | dinv[100k] |
    // buf[NBKT*CAP] | g1h[800k int] | g2h[800k int]  (~34MB)
    int*      gcursor  = (int*)d_ws;
    int*      nodeinfo = gcursor + 1024;
    float*    dinv     = (float*)(nodeinfo + N_NODES);
    int*      buf      = (int*)(dinv + N_NODES);
    __half*   g1h      = (__half*)(buf + (size_t)NBKT * CAP);
    __half*   g2h      = g1h + (size_t)N_NODES * HIDDEN;

    const int NB_LN = (N_NODES + 63) / 64;             // 1563 (64 nodes/block)
    const int NB_PULL = N_NODES / 16;                  // 6250 (pull: 16 nodes/block)
    const int NB_P1 = (N_EDGES + P1_EPB - 1) / P1_EPB; // 521

    initcur_kernel<<<1, 1024, 0, stream>>>(gcursor);
    part1_kernel<<<NB_P1, 512, 0, stream>>>(src, dst, gcursor, buf);
    part2_kernel<<<NBKT, 512, 0, stream>>>(gcursor, buf, nodeinfo, dinv);
    ln_w1_kernel<<<NB_LN, 256, 0, stream>>>(x, gamma, beta, W1, dinv, g1h);
    pull1_kernel<<<NB_PULL, 256, 0, stream>>>(nodeinfo, buf, g1h,
                                              dinv, b1, W2, dk1_0, dk1_1, g2h);
    pull2_kernel<<<NB_PULL, 256, 0, stream>>>(nodeinfo, buf, g2h,
                                              dinv, b2, dk2_0, dk2_1, out);
}

// Round 13
// 258.263 us; speedup vs baseline: 1.0826x; 1.0826x over previous
//
#include <hip/hip_runtime.h>
#include <hip/hip_fp16.h>
#include <stdint.h>
#include <stddef.h>

#define N_NODES 100000
#define N_EDGES 6400000
#define HIDDEN 16
#define NBKT 782          /* ceil(100000/128) coarse buckets of 128 nodes */
#define CAP 8704          /* bucket region capacity: mean 8184 + 5.7 sigma */
#define P1_EPB 12288      /* edges per part1 block (48KB lsort, 60.3KB LDS) */

typedef _Float16 f16x8 __attribute__((ext_vector_type(8)));
typedef _Float16 f16x4 __attribute__((ext_vector_type(4)));
typedef float f32x4 __attribute__((ext_vector_type(4)));

__host__ __device__ inline uint32_t rotl32(uint32_t x, int n) {
    return (x << n) | (x >> (32 - n));
}

// Exact JAX threefry2x32 (20 rounds)
__host__ __device__ inline void threefry2x32(uint32_t k0, uint32_t k1,
                                             uint32_t x0, uint32_t x1,
                                             uint32_t& o0, uint32_t& o1) {
    uint32_t k2 = k0 ^ k1 ^ 0x1BD11BDAu;
    x0 += k0; x1 += k1;
    x0 += x1; x1 = rotl32(x1, 13); x1 ^= x0;
    x0 += x1; x1 = rotl32(x1, 15); x1 ^= x0;
    x0 += x1; x1 = rotl32(x1, 26); x1 ^= x0;
    x0 += x1; x1 = rotl32(x1,  6); x1 ^= x0;
    x0 += k1; x1 += k2 + 1u;
    x0 += x1; x1 = rotl32(x1, 17); x1 ^= x0;
    x0 += x1; x1 = rotl32(x1, 29); x1 ^= x0;
    x0 += x1; x1 = rotl32(x1, 16); x1 ^= x0;
    x0 += x1; x1 = rotl32(x1, 24); x1 ^= x0;
    x0 += k2; x1 += k0 + 2u;
    x0 += x1; x1 = rotl32(x1, 13); x1 ^= x0;
    x0 += x1; x1 = rotl32(x1, 15); x1 ^= x0;
    x0 += x1; x1 = rotl32(x1, 26); x1 ^= x0;
    x0 += x1; x1 = rotl32(x1,  6); x1 ^= x0;
    x0 += k0; x1 += k1 + 3u;
    x0 += x1; x1 = rotl32(x1, 17); x1 ^= x0;
    x0 += x1; x1 = rotl32(x1, 29); x1 ^= x0;
    x0 += x1; x1 = rotl32(x1, 16); x1 ^= x0;
    x0 += x1; x1 = rotl32(x1, 24); x1 ^= x0;
    x0 += k1; x1 += k2 + 4u;
    x0 += x1; x1 = rotl32(x1, 13); x1 ^= x0;
    x0 += x1; x1 = rotl32(x1, 15); x1 ^= x0;
    x0 += x1; x1 = rotl32(x1, 26); x1 ^= x0;
    x0 += x1; x1 = rotl32(x1,  6); x1 ^= x0;
    x0 += k2; x1 += k0 + 5u;
    o0 = x0; o1 = x1;
}

// dropout keep decision for flattened element j (bit-exact vs dropmask)
__device__ inline bool keep_bit(uint32_t k0, uint32_t k1, uint32_t j) {
    uint32_t a, b;
    threefry2x32(k0, k1, 0u, j, a, b);
    uint32_t bits = a ^ b;
    float u = __uint_as_float((bits >> 9) | 0x3F800000u) - 1.0f;
    return u >= 0.3f;
}

// ---- gcursor[b] = b*CAP (fixed-capacity bucket regions, no scan) ---------
__global__ void initcur_kernel(int* __restrict__ gcursor) {
    int b = threadIdx.x;
    if (b < NBKT) gcursor[b] = b * CAP;
}

// ---- partition pass 1: LDS counting sort, reg-cached dst, shuffle scan ---
// R9 lesson: occupancy is NOT the limiter (65% occ ran 40% SLOWER than 39%).
// R10: dst int4s cached in registers between hist and scatter passes; EPB
// 12288 cuts per-block fixed costs and lengthens write runs.
// lsort staging is load-bearing: 43MB writes with it vs 172MB without (R3).
__global__ __launch_bounds__(512) void part1_kernel(const int* __restrict__ src,
                                                    const int* __restrict__ dst,
                                                    int* __restrict__ gcursor,
                                                    int* __restrict__ buf) {
    __shared__ int lhist[NBKT], lbase[NBKT], lstart[NBKT], lcur[NBKT];
    __shared__ int wsum[8];
    __shared__ int lsort[P1_EPB];
    int tid = threadIdx.x;
    const int NV4 = N_EDGES >> 2;                 // 1.6M int4 groups
    int base4 = blockIdx.x * (P1_EPB >> 2);       // 3072 int4 per block
    const int4* dst4 = (const int4*)dst;
    const int4* src4 = (const int4*)src;

    for (int b = tid; b < NBKT; b += 512) lhist[b] = 0;
    __syncthreads();
    int4 dc[6];                                   // register dst cache
    #pragma unroll
    for (int i = 0; i < 6; i++) {
        int e4 = base4 + i * 512 + tid;
        if (e4 < NV4) dc[i] = dst4[e4];
    }
    #pragma unroll
    for (int i = 0; i < 6; i++) {
        int e4 = base4 + i * 512 + tid;
        if (e4 < NV4) {
            atomicAdd(&lhist[dc[i].x >> 7], 1);
            atomicAdd(&lhist[dc[i].y >> 7], 1);
            atomicAdd(&lhist[dc[i].z >> 7], 1);
            atomicAdd(&lhist[dc[i].w >> 7], 1);
        }
    }
    __syncthreads();
    // exclusive scan over 782 bucket counts: thread t owns buckets 2t,2t+1
    int i0 = tid * 2, i1 = i0 + 1;
    int c0 = (i0 < NBKT) ? lhist[i0] : 0;
    int c1 = (i1 < NBKT) ? lhist[i1] : 0;
    int v = c0 + c1;
    int lane = tid & 63, wid = tid >> 6;
    int sc = v;
    #pragma unroll
    for (int o = 1; o < 64; o <<= 1) {
        int t2 = __shfl_up(sc, o, 64);
        if (lane >= o) sc += t2;
    }
    if (lane == 63) wsum[wid] = sc;
    __syncthreads();
    int wo = 0;
    #pragma unroll
    for (int w = 0; w < 8; w++) wo += (w < wid) ? wsum[w] : 0;
    int excl = sc - v + wo;
    if (i0 < NBKT) { lstart[i0] = excl;      lcur[i0] = excl; }
    if (i1 < NBKT) { lstart[i1] = excl + c0; lcur[i1] = excl + c0; }
    for (int b = tid; b < NBKT; b += 512) {
        int c = lhist[b];
        lbase[b] = c ? atomicAdd(&gcursor[b], c) : 0;
    }
    __syncthreads();
    // scatter: atomics start immediately on cached dst; src loads overlap
    #pragma unroll
    for (int i = 0; i < 6; i++) {
        int e4 = base4 + i * 512 + tid;
        if (e4 < NV4) {
            int4 s = src4[e4];
            int4 d = dc[i];
            int p0 = atomicAdd(&lcur[d.x >> 7], 1);
            int p1 = atomicAdd(&lcur[d.y >> 7], 1);
            int p2 = atomicAdd(&lcur[d.z >> 7], 1);
            int p3 = atomicAdd(&lcur[d.w >> 7], 1);
            lsort[p0] = ((d.x & 127) << 17) | s.x;
            lsort[p1] = ((d.y & 127) << 17) | s.y;
            lsort[p2] = ((d.z & 127) << 17) | s.z;
            lsort[p3] = ((d.w & 127) << 17) | s.w;
        }
    }
    __syncthreads();
    int grp = tid >> 4, gl = tid & 15;
    for (int b = grp; b < NBKT; b += 32) {
        int st = lstart[b], c = lhist[b], gb = lbase[b];
        int lim = (b + 1) * CAP;
        for (int k = gl; k < c; k += 16) {
            int pos = gb + k;
            if (pos < lim)   // capacity guard (P ~ 5e-6 total)
                buf[pos] = lsort[st + k];
        }
    }
}

// ---- part2: per-bucket fine sort in LDS; reg-cached buf, shuffle scan ----
__global__ __launch_bounds__(512) void part2_kernel(const int* __restrict__ gcursor,
                                                    int* __restrict__ buf,
                                                    int* __restrict__ nodeinfo,
                                                    float* __restrict__ dinv) {
    __shared__ int lcnt[128], lcur[128];
    __shared__ int w0sum;
    __shared__ int lsort[CAP];
    int b = blockIdx.x, tid = threadIdx.x;
    int base = b * CAP;                 // CAP%4==0 -> 16B aligned
    int end = gcursor[b];
    int count = end - base;
    if (count > CAP) count = CAP;       // memory-safety clamp
    int cnt4 = count >> 2;              // <= 2176 -> <= 5 iters of 512
    const int4* buf4 = (const int4*)(buf + base);
    if (tid < 128) lcnt[tid] = 0;
    __syncthreads();
    int4 rc[5];                          // register cache (static idx only)
    #pragma unroll
    for (int it = 0; it < 5; it++) {
        int i = tid + it * 512;
        if (i < cnt4) rc[it] = buf4[i];
    }
    #pragma unroll
    for (int it = 0; it < 5; it++) {
        int i = tid + it * 512;
        if (i < cnt4) {
            atomicAdd(&lcnt[rc[it].x >> 17], 1);
            atomicAdd(&lcnt[rc[it].y >> 17], 1);
            atomicAdd(&lcnt[rc[it].z >> 17], 1);
            atomicAdd(&lcnt[rc[it].w >> 17], 1);
        }
    }
    for (int i = (cnt4 << 2) + tid; i < count; i += 512)
        atomicAdd(&lcnt[buf[base + i] >> 17], 1);
    __syncthreads();
    // shuffle scan over 128 counters (waves 0 and 1)
    if (tid < 128) {
        int v = lcnt[tid];
        int lane = tid & 63;
        int sc = v;
        #pragma unroll
        for (int o = 1; o < 64; o <<= 1) {
            int t2 = __shfl_up(sc, o, 64);
            if (lane >= o) sc += t2;
        }
        if (tid == 63) w0sum = sc;
        __syncthreads();
        int incl = sc + ((tid >= 64) ? w0sum : 0);
        int excl = incl - v;
        lcur[tid] = excl;
        int n = b * 128 + tid;
        if (n < N_NODES) {
            nodeinfo[n] = (v << 23) | (base + excl);
            dinv[n] = rsqrtf((float)v + 1.0f);  // +1 self-loop
        }
    } else {
        __syncthreads();
    }
    __syncthreads();
    #pragma unroll
    for (int it = 0; it < 5; it++) {
        int i = tid + it * 512;
        if (i < cnt4) {
            int4 w = rc[it];
            int p0 = atomicAdd(&lcur[w.x >> 17], 1); lsort[p0] = w.x & 0x1FFFF;
            int p1 = atomicAdd(&lcur[w.y >> 17], 1); lsort[p1] = w.y & 0x1FFFF;
            int p2 = atomicAdd(&lcur[w.z >> 17], 1); lsort[p2] = w.z & 0x1FFFF;
            int p3 = atomicAdd(&lcur[w.w >> 17], 1); lsort[p3] = w.w & 0x1FFFF;
        }
    }
    for (int i = (cnt4 << 2) + tid; i < count; i += 512) {
        int w = buf[base + i];
        int pos = atomicAdd(&lcur[w >> 17], 1);
        lsort[pos] = w & 0x1FFFF;
    }
    __syncthreads();
    int4* bufw4 = (int4*)(buf + base);
    const int4* lsort4 = (const int4*)lsort;
    for (int i = tid; i < cnt4; i += 512) bufw4[i] = lsort4[i];
    for (int i = (cnt4 << 2) + tid; i < count; i += 512) buf[base + i] = lsort[i];
}

// ---- LayerNorm + W1 via MFMA: 64 nodes per 256-thread block --------------
// Coalesced one-touch x load (slot-major): thread t slot j holds float4
// idx = j*256+t -> each load instr covers 4KB contiguous (R6 fix: the
// quarter-row mapping fetched 108MB = 2.1x input). Slot j of thread t holds
// row 8j+(t>>5), col (t&31)*4 -> LN stats = 32-lane shfl_xor butterfly.
#define XSTR 136
__global__ __launch_bounds__(256) void ln_w1_kernel(const float* __restrict__ x,
                             const float* __restrict__ gamma,
                             const float* __restrict__ beta,
                             const float* __restrict__ W1,
                             const float* __restrict__ dinv,
                             __half* __restrict__ g1) {
    __shared__ __align__(16) _Float16 xnh[64 * XSTR];   // 17408 B
    __shared__ __align__(16) _Float16 w1t[16 * XSTR];   //  4352 B
    int tid = threadIdx.x;

    // stage W1^T as f16: thread (n=tid&15, kb=tid>>4) covers 8 k's
    {
        int n = tid & 15, kb = tid >> 4;
        f16x8 wv;
        #pragma unroll
        for (int j = 0; j < 8; j++)
            wv[j] = (_Float16)W1[(kb * 8 + j) * 16 + n];
        *(f16x8*)&w1t[n * XSTR + kb * 8] = wv;
    }

    // coalesced loads: 8 x (256 lanes x 16B) = the full 32KB tile, one touch
    const float4* xt = (const float4*)x;
    size_t base4 = (size_t)blockIdx.x * 2048;
    const size_t NF4 = (size_t)N_NODES * 32;
    float4 v[8];
    #pragma unroll
    for (int j = 0; j < 8; j++) {
        size_t idx = base4 + (size_t)j * 256 + tid;
        v[j] = (idx < NF4) ? xt[idx] : make_float4(0.f, 0.f, 0.f, 0.f);
    }
    int col = tid & 31;            // float4 column within row
    int sub = tid >> 5;            // row sub-index within slot
    float4 gv = ((const float4*)gamma)[col];
    float4 bv = ((const float4*)beta)[col];
    #pragma unroll
    for (int j = 0; j < 8; j++) {
        float s1 = v[j].x + v[j].y + v[j].z + v[j].w;
        float s2 = v[j].x * v[j].x + v[j].y * v[j].y
                 + v[j].z * v[j].z + v[j].w * v[j].w;
        #pragma unroll
        for (int o = 1; o < 32; o <<= 1) {      // 32-lane row butterfly
            s1 += __shfl_xor(s1, o, 64);
            s2 += __shfl_xor(s2, o, 64);
        }
        float mu = s1 * (1.0f / 128.0f);
        float var = s2 * (1.0f / 128.0f) - mu * mu;
        float rstd = rsqrtf(var + 1e-5f);
        int row = j * 8 + sub;
        f16x4 h;
        h[0] = (_Float16)((v[j].x - mu) * rstd * gv.x + bv.x);
        h[1] = (_Float16)((v[j].y - mu) * rstd * gv.y + bv.y);
        h[2] = (_Float16)((v[j].z - mu) * rstd * gv.z + bv.z);
        h[3] = (_Float16)((v[j].w - mu) * rstd * gv.w + bv.w);
        *(f16x4*)&xnh[row * XSTR + col * 4] = h;
    }
    __syncthreads();

    // MFMA phase: wave w -> rows 16w..16w+15
    int l = tid & 63, w = tid >> 6;
    int am = l & 15, ak = l >> 4;   // A row / k-subgroup
    const _Float16* abase = &xnh[(w * 16 + am) * XSTR + ak * 8];
    const _Float16* bbase = &w1t[am * XSTR + ak * 8];
    f32x4 acc = {0.f, 0.f, 0.f, 0.f};
    #pragma unroll
    for (int kk = 0; kk < 4; kk++) {
        f16x8 av = *(const f16x8*)(abase + kk * 32);
        f16x8 bv2 = *(const f16x8*)(bbase + kk * 32);
        acc = __builtin_amdgcn_mfma_f32_16x16x32_f16(av, bv2, acc, 0, 0, 0);
    }
    _Float16* g1h = (_Float16*)g1;
    #pragma unroll
    for (int reg = 0; reg < 4; reg++) {
        int row = w * 16 + ak * 4 + reg;            // C: row=(l>>4)*4+reg
        int nn = blockIdx.x * 64 + row;
        if (nn < N_NODES)
            g1h[nn * 16 + am] = (_Float16)(acc[reg] * dinv[nn]);  // col=l&15
    }
}

// ---- pull conv1 + fused finalize1: 4 nodes/wave, 2x16B gather per row ----
// R12 lesson: nt loads + 32-unroll regressed (wasted clamped loads + L1
// bypass on idx). R13: back to 16-edge chunks + SOFTWARE-PIPELINED idx
// prefetch — chunk i+1's idx loads issue before chunk i's gathers, so the
// gather never waits on an idx in flight (critical path idx_lat+gather_lat
// -> max of the two).
__global__ __launch_bounds__(256) void pull1_kernel(const int* __restrict__ nodeinfo,
                             const int* __restrict__ sorted_src,
                             const __half* __restrict__ g1,
                             const float* __restrict__ dinv,
                             const float* __restrict__ b1,
                             const float* __restrict__ W2,
                             uint32_t k10, uint32_t k11,
                             __half* __restrict__ g2) {
    __shared__ float sW2[HIDDEN * HIDDEN];
    sW2[threadIdx.x] = W2[threadIdx.x];     // 256 threads == 256 elems
    __syncthreads();
    int n = blockIdx.x * 16 + (threadIdx.x >> 4);  // grid*16 == N_NODES
    int l = threadIdx.x & 15;
    int c2 = l & 1, e8 = l >> 1;
    const _Float16* gt = (const _Float16*)g1;
    int info = nodeinfo[n];
    int start = info & 0x7FFFFF;
    int deg = (int)((unsigned)info >> 23);

    float acc[8] = {0.f,0.f,0.f,0.f,0.f,0.f,0.f,0.f};
    float acc2[8] = {0.f,0.f,0.f,0.f,0.f,0.f,0.f,0.f};
    if (e8 == 0) {                                  // self row, lanes 0,1
        f16x8 sv = *(const f16x8*)(gt + (uint32_t)n * 16 + c2 * 8);
        #pragma unroll
        for (int j = 0; j < 8; j++) acc[j] = (float)sv[j];
    }
    int km = (deg > 0) ? deg - 1 : 0;
    // prefetch chunk 0 indices
    int s0 = sorted_src[start + min(e8, km)];
    int s1 = sorted_src[start + min(8 + e8, km)];
    for (int kb = 0; kb < deg; kb += 16) {
        int cs0 = s0, cs1 = s1;
        // issue chunk i+1 idx loads (addresses independent of gathers)
        s0 = sorted_src[start + min(kb + 16 + e8, km)];
        s1 = sorted_src[start + min(kb + 24 + e8, km)];
        int k0 = kb + e8, k1 = kb + 8 + e8;
        if (k0 < deg) {
            f16x8 gv = *(const f16x8*)(gt + (uint32_t)cs0 * 16 + c2 * 8);
            #pragma unroll
            for (int j = 0; j < 8; j++) acc[j] += (float)gv[j];
        }
        if (k1 < deg) {
            f16x8 gv = *(const f16x8*)(gt + (uint32_t)cs1 * 16 + c2 * 8);
            #pragma unroll
            for (int j = 0; j < 8; j++) acc2[j] += (float)gv[j];
        }
    }
    #pragma unroll
    for (int j = 0; j < 8; j++) acc[j] += acc2[j];
    // halving butterfly over e8: xor 2, 4, 8
    float h4[4];
    {
        int sel = e8 & 1;
        #pragma unroll
        for (int j = 0; j < 4; j++) {
            float mine = sel ? acc[j + 4] : acc[j];
            float give = sel ? acc[j] : acc[j + 4];
            h4[j] = mine + __shfl_xor(give, 2, 64);
        }
    }
    float h2[2];
    {
        int sel = (e8 >> 1) & 1;
        #pragma unroll
        for (int j = 0; j < 2; j++) {
            float mine = sel ? h4[j + 2] : h4[j];
            float give = sel ? h4[j] : h4[j + 2];
            h2[j] = mine + __shfl_xor(give, 4, 64);
        }
    }
    float hv;
    {
        int sel = (e8 >> 2) & 1;
        float mine = sel ? h2[1] : h2[0];
        float give = sel ? h2[0] : h2[1];
        hv = mine + __shfl_xor(give, 8, 64);
    }
    // lane l holds component cc
    int cc = c2 * 8 + (e8 & 1) * 4 + ((e8 >> 1) & 1) * 2 + ((e8 >> 2) & 1);
    float di = dinv[n];
    bool kp = keep_bit(k10, k11, (uint32_t)(n * 16 + cc));
    float hd = kp ? fmaxf(di * hv + b1[cc], 0.f) * (1.0f / 0.7f) : 0.f;
    // h @ W2: broadcast hd from bit-reversed lane per i (compile-time)
    int grpbase = threadIdx.x & 48;
    int c = l & 3;
    float4 o4 = make_float4(0.f, 0.f, 0.f, 0.f);
    #pragma unroll
    for (int i = 0; i < 16; i++) {
        int srcl = grpbase + (((i >> 3) & 1) | (((i >> 2) & 1) << 1) |
                              (((i >> 1) & 1) << 2) | ((i & 1) << 3));
        float hi = __shfl(hd, srcl, 64);
        const float4 w = *(const float4*)&sW2[i * HIDDEN + c * 4];
        o4.x += hi * w.x; o4.y += hi * w.y; o4.z += hi * w.z; o4.w += hi * w.w;
    }
    if (l < 4) {
        __half2 p0 = __floats2half2_rn(o4.x * di, o4.y * di);
        __half2 p1 = __floats2half2_rn(o4.z * di, o4.w * di);
        uint2 u;
        u.x = *(uint32_t*)&p0; u.y = *(uint32_t*)&p1;
        *(uint2*)((__half*)g2 + (uint32_t)n * 16 + c * 4) = u;
    }
}

// ---- pull conv2 + fused finalize2: same pipelined layout, fp32 output ----
__global__ __launch_bounds__(256) void pull2_kernel(const int* __restrict__ nodeinfo,
                             const int* __restrict__ sorted_src,
                             const __half* __restrict__ g2,
                             const float* __restrict__ dinv,
                             const float* __restrict__ b2,
                             uint32_t k20, uint32_t k21,
                             float* __restrict__ out) {
    int n = blockIdx.x * 16 + (threadIdx.x >> 4);
    int l = threadIdx.x & 15;
    int c2 = l & 1, e8 = l >> 1;
    const _Float16* gt = (const _Float16*)g2;
    int info = nodeinfo[n];
    int start = info & 0x7FFFFF;
    int deg = (int)((unsigned)info >> 23);

    float acc[8] = {0.f,0.f,0.f,0.f,0.f,0.f,0.f,0.f};
    float acc2[8] = {0.f,0.f,0.f,0.f,0.f,0.f,0.f,0.f};
    if (e8 == 0) {                                  // self row
        f16x8 sv = *(const f16x8*)(gt + (uint32_t)n * 16 + c2 * 8);
        #pragma unroll
        for (int j = 0; j < 8; j++) acc[j] = (float)sv[j];
    }
    int km = (deg > 0) ? deg - 1 : 0;
    int s0 = sorted_src[start + min(e8, km)];
    int s1 = sorted_src[start + min(8 + e8, km)];
    for (int kb = 0; kb < deg; kb += 16) {
        int cs0 = s0, cs1 = s1;
        s0 = sorted_src[start + min(kb + 16 + e8, km)];
        s1 = sorted_src[start + min(kb + 24 + e8, km)];
        int k0 = kb + e8, k1 = kb + 8 + e8;
        if (k0 < deg) {
            f16x8 gv = *(const f16x8*)(gt + (uint32_t)cs0 * 16 + c2 * 8);
            #pragma unroll
            for (int j = 0; j < 8; j++) acc[j] += (float)gv[j];
        }
        if (k1 < deg) {
            f16x8 gv = *(const f16x8*)(gt + (uint32_t)cs1 * 16 + c2 * 8);
            #pragma unroll
            for (int j = 0; j < 8; j++) acc2[j] += (float)gv[j];
        }
    }
    #pragma unroll
    for (int j = 0; j < 8; j++) acc[j] += acc2[j];
    float h4[4];
    {
        int sel = e8 & 1;
        #pragma unroll
        for (int j = 0; j < 4; j++) {
            float mine = sel ? acc[j + 4] : acc[j];
            float give = sel ? acc[j] : acc[j + 4];
            h4[j] = mine + __shfl_xor(give, 2, 64);
        }
    }
    float h2[2];
    {
        int sel = (e8 >> 1) & 1;
        #pragma unroll
        for (int j = 0; j < 2; j++) {
            float mine = sel ? h4[j + 2] : h4[j];
            float give = sel ? h4[j] : h4[j + 2];
            h2[j] = mine + __shfl_xor(give, 4, 64);
        }
    }
    float hv;
    {
        int sel = (e8 >> 2) & 1;
        float mine = sel ? h2[1] : h2[0];
        float give = sel ? h2[0] : h2[1];
        hv = mine + __shfl_xor(give, 8, 64);
    }
    int cc = c2 * 8 + (e8 & 1) * 4 + ((e8 >> 1) & 1) * 2 + ((e8 >> 2) & 1);
    float di = dinv[n];
    bool kp = keep_bit(k20, k21, (uint32_t)(n * 16 + cc));
    float r = kp ? fmaxf(di * hv + b2[cc], 0.f) * (1.0f / 0.7f) : 0.f;
    out[(uint32_t)n * 16 + cc] = r;   // 16 lanes cover one 64B line
}

extern "C" void kernel_launch(void* const* d_in, const int* in_sizes, int n_in,
                              void* d_out, int out_size, void* d_ws, size_t ws_size,
                              hipStream_t stream) {
    const float* x     = (const float*)d_in[0];
    const int*   ei    = (const int*)d_in[1];
    const float* gamma = (const float*)d_in[2];
    const float* beta  = (const float*)d_in[3];
    const float* W1    = (const float*)d_in[4];
    const float* b1    = (const float*)d_in[5];
    const float* W2    = (const float*)d_in[6];
    const float* b2    = (const float*)d_in[7];
    float* out = (float*)d_out;
    const int* src = ei;
    const int* dst = ei + N_EDGES;

    uint32_t dk1_0, dk1_1, dk2_0, dk2_1;
    threefry2x32(0u, 42u, 0u, 0u, dk1_0, dk1_1);
    threefry2x32(0u, 42u, 0u, 1u, dk2_0, dk2_1);

    // ws layout (4B elems): gcursor[1024] | nodeinfo[100k] | dinv[100k] |
    // buf[NBKT*CAP] | g1h[800k int] | g2h[800k int]  (~34MB)
    int*      gcursor  = (int*)d_ws;
    int*      nodeinfo = gcursor + 1024;
    float*    dinv     = (float*)(nodeinfo + N_NODES);
    int*      buf      = (int*)(dinv + N_NODES);
    __half*   g1h      = (__half*)(buf + (size_t)NBKT * CAP);
    __half*   g2h      = g1h + (size_t)N_NODES * HIDDEN;

    const int NB_LN = (N_NODES + 63) / 64;             // 1563 (64 nodes/block)
    const int NB_PULL = N_NODES / 16;                  // 6250 (pull: 16 nodes/block)
    const int NB_P1 = (N_EDGES + P1_EPB - 1) / P1_EPB; // 521

    initcur_kernel<<<1, 1024, 0, stream>>>(gcursor);
    part1_kernel<<<NB_P1, 512, 0, stream>>>(src, dst, gcursor, buf);
    part2_kernel<<<NBKT, 512, 0, stream>>>(gcursor, buf, nodeinfo, dinv);
    ln_w1_kernel<<<NB_LN, 256, 0, stream>>>(x, gamma, beta, W1, dinv, g1h);
    pull1_kernel<<<NB_PULL, 256, 0, stream>>>(nodeinfo, buf, g1h,
                                              dinv, b1, W2, dk1_0, dk1_1, g2h);
    pull2_kernel<<<NB_PULL, 256, 0, stream>>>(nodeinfo, buf, g2h,
                                              dinv, b2, dk2_0, dk2_1, out);
}